// Round 10
// baseline (187.347 us; speedup 1.0000x reference)
//
#include <hip/hip_runtime.h>
#include <math.h>

#define B_  2
#define Q_  2048
#define CQ_ 512
#define H_  8
#define D_  64
#define M_  (B_*Q_)   // 4096
#define L2E 1.44269504088896f

typedef __bf16 bf16;
typedef __bf16 bf16x4 __attribute__((ext_vector_type(4)));
typedef __bf16 bf16x8 __attribute__((ext_vector_type(8)));
typedef float  f32x4  __attribute__((ext_vector_type(4)));
typedef float  f32x16 __attribute__((ext_vector_type(16)));

// async global->LDS, 16 bytes per lane; lds dest = wave-uniform base + lane*16
__device__ __forceinline__ void gl_lds16(const bf16* g, bf16* l) {
    __builtin_amdgcn_global_load_lds(
        (const __attribute__((address_space(1))) unsigned int*)g,
        (__attribute__((address_space(3))) unsigned int*)l, 16, 0, 0);
}

__device__ __forceinline__ bf16x4 shfl_xor32(bf16x4 v) {
    union { bf16x4 h; int i[2]; } u;
    u.h = v;
    u.i[0] = __shfl_xor(u.i[0], 32, 64);
    u.i[1] = __shfl_xor(u.i[1], 32, 64);
    return u.h;
}

// ---------------------------------------------------------------------------
// fp32 -> bf16 conversion into K-panel-packed layouts (pack = LDS image):
//   pack_off(row, k; R) = (k>>5)*(R*32) + row*32 + (k&31)
// ---------------------------------------------------------------------------
#define S0 (4096*512)    // q_x
#define S1 (1536*512)    // w_qkv
#define S2 (512*512)     // w_g
#define S3 (512*512)     // w_o
__global__ __launch_bounds__(256)
void convert_kernel(const float* __restrict__ qx, const float* __restrict__ wqkv,
                    const float* __restrict__ wg, const float* __restrict__ wo,
                    bf16* __restrict__ qxb, bf16* __restrict__ wcat, bf16* __restrict__ wob)
{
    const long long t = (long long)blockIdx.x * 256 + threadIdx.x;
    const long long e = t * 8;
    const float* src; bf16* dst;
    if (e < S0) {
        const int m = (int)(e >> 9), k = (int)(e & 511);
        src = qx + e;
        dst = qxb + (size_t)(k >> 5) * (4096 * 32) + (size_t)m * 32 + (k & 31);
    } else if (e < S0 + S1) {
        const long long e2 = e - S0;
        const int n = (int)(e2 >> 9), k = (int)(e2 & 511);
        src = wqkv + e2;
        dst = wcat + (size_t)(k >> 5) * (2048 * 32) + (size_t)n * 32 + (k & 31);
    } else if (e < S0 + S1 + S2) {
        const long long e2 = e - S0 - S1;
        const int n = 1536 + (int)(e2 >> 9), k = (int)(e2 & 511);
        src = wg + e2;
        dst = wcat + (size_t)(k >> 5) * (2048 * 32) + (size_t)n * 32 + (k & 31);
    } else {
        const long long e2 = e - S0 - S1 - S2;
        const int n = (int)(e2 >> 9), k = (int)(e2 & 511);
        src = wo + e2;
        dst = wob + (size_t)(k >> 5) * (512 * 32) + (size_t)n * 32 + (k & 31);
    }
    const float4 a = *(const float4*)(src);
    const float4 b = *(const float4*)(src + 4);
    bf16x8 v;
    v[0] = (bf16)a.x; v[1] = (bf16)a.y; v[2] = (bf16)a.z; v[3] = (bf16)a.w;
    v[4] = (bf16)b.x; v[5] = (bf16)b.y; v[6] = (bf16)b.z; v[7] = (bf16)b.w;
    *(bf16x8*)dst = v;
}

// ---------------------------------------------------------------------------
// bf16 MFMA GEMM, DOUBLE-BUFFERED K-loop: stage k0+1 while computing k0.
// C[M,N] = A[M,512]*W[N,512]^T, BK=32. W always packed (WNR rows); A packed
// iff APACK. All parts except V compute C^T (swapped operands).
// EPI 0: n<512 q | <1024 k(frag) | <1536 v(frag) | else gate.  EPI 1: +b_o.
// ---------------------------------------------------------------------------
template<int BM, int BN, int EPI, int WNR, int APACK>
__global__ __launch_bounds__(256)
void gemm_bf16(const bf16* __restrict__ A, const bf16* __restrict__ W,
               const float* __restrict__ bvec, float* __restrict__ fout,
               bf16* __restrict__ qb, bf16* __restrict__ kb, bf16* __restrict__ vb,
               bf16* __restrict__ gb)
{
    constexpr int MI = BM / 32, NJ = BN / 32;
    constexpr int APARTS = BM / 16, BPARTS = BN / 16, NPARTS = APARTS + BPARTS;
    __shared__ __align__(16) bf16 As[2][BM * 32];
    __shared__ __align__(16) bf16 Bs[2][BN * 32];

    const int t = threadIdx.x;
    const int w = t >> 6, lane = t & 63;
    const int l15 = lane & 15, quad = lane >> 4;
    const int wm = w & 1, wn = w >> 1;
    const int bm = blockIdx.x * BM;
    const int bn = blockIdx.y * BN;
    const bool swapped = (EPI == 1) || ((bn >> 9) != 2);

    f32x4 acc[MI][NJ] = {};

    auto stage = [&](int kp, int buf) {
        #pragma unroll
        for (int idx = 0; idx < NPARTS / 4; ++idx) {
            const int p = idx * 4 + w;
            if (p < APARTS) {
                if constexpr (APACK)
                    gl_lds16(A + (size_t)kp * (4096 * 32) + (size_t)bm * 32 + p * 512 + lane * 8,
                             As[buf] + p * 512);
                else
                    gl_lds16(A + (size_t)(bm + p * 16 + (lane >> 2)) * 512 + kp * 32 + (lane & 3) * 8,
                             As[buf] + p * 512);
            } else {
                gl_lds16(W + (size_t)kp * (WNR * 32) + (size_t)bn * 32 + (p - APARTS) * 512 + lane * 8,
                         Bs[buf] + (p - APARTS) * 512);
            }
        }
    };

    stage(0, 0);
    __asm__ volatile("s_waitcnt vmcnt(0)" ::: "memory");
    __syncthreads();

    int cur = 0;
    #pragma unroll 1
    for (int kp = 0; kp < 16; ++kp) {
        if (kp < 15) stage(kp + 1, cur ^ 1);

        bf16x8 af[MI], bfr[NJ];
        #pragma unroll
        for (int i = 0; i < MI; ++i)
            af[i] = *(const bf16x8*)(As[cur] + (wm * (BM / 2) + i * 16 + l15) * 32 + quad * 8);
        #pragma unroll
        for (int j = 0; j < NJ; ++j)
            bfr[j] = *(const bf16x8*)(Bs[cur] + (wn * (BN / 2) + j * 16 + l15) * 32 + quad * 8);
        if (swapped) {
            #pragma unroll
            for (int i = 0; i < MI; ++i)
                #pragma unroll
                for (int j = 0; j < NJ; ++j)
                    acc[i][j] = __builtin_amdgcn_mfma_f32_16x16x32_bf16(bfr[j], af[i], acc[i][j], 0, 0, 0);
        } else {
            #pragma unroll
            for (int i = 0; i < MI; ++i)
                #pragma unroll
                for (int j = 0; j < NJ; ++j)
                    acc[i][j] = __builtin_amdgcn_mfma_f32_16x16x32_bf16(af[i], bfr[j], acc[i][j], 0, 0, 0);
        }
        __asm__ volatile("s_waitcnt vmcnt(0)" ::: "memory");
        __syncthreads();
        cur ^= 1;
    }

    if (swapped) {
        #pragma unroll
        for (int i = 0; i < MI; ++i) {
            const int m = bm + wm * (BM / 2) + i * 16 + l15;
            const int b = m >> 11, qq = m & 2047;
            #pragma unroll
            for (int j = 0; j < NJ; ++j) {
                const int n0 = bn + wn * (BN / 2) + j * 16 + quad * 4;
                const f32x4 cv = acc[i][j];
                if constexpr (EPI == 1) {
                    float4 st;
                    st.x = cv[0] + bvec[n0 + 0];
                    st.y = cv[1] + bvec[n0 + 1];
                    st.z = cv[2] + bvec[n0 + 2];
                    st.w = cv[3] + bvec[n0 + 3];
                    *(float4*)(fout + (size_t)m * 512 + n0) = st;
                } else {
                    const int part = n0 >> 9;
                    if (part == 0) {
                        const int h = (n0 >> 6) & 7, d0 = n0 & 63;
                        bf16x4 q4;
                        #pragma unroll
                        for (int r = 0; r < 4; ++r) q4[r] = (bf16)(cv[r] * (0.125f * L2E));
                        *(bf16x4*)(qb + (size_t)(b * H_ + h) * (Q_ * D_) + (size_t)qq * 64 + d0) = q4;
                    } else if (part == 1) {
                        const int h = (n0 >> 6) & 7, d0 = n0 & 63;
                        const size_t off = (size_t)(b * H_ + h) * (Q_ * D_)
                            + (qq >> 6) * 4096 + ((qq >> 5) & 1) * 2048
                            + (d0 >> 4) * 512 + ((d0 >> 3) & 1) * 256
                            + (qq & 31) * 8 + (d0 & 7);
                        bf16x4 k4;
                        #pragma unroll
                        for (int r = 0; r < 4; ++r) k4[r] = (bf16)cv[r];
                        *(bf16x4*)(kb + off) = k4;
                    } else {
                        const int gcol = n0 & 511;
                        const float4 bv4 = *(const float4*)(bvec + gcol);
                        bf16x4 g4;
                        g4[0] = (bf16)(1.f / (1.f + __expf(-(cv[0] + bv4.x))));
                        g4[1] = (bf16)(1.f / (1.f + __expf(-(cv[1] + bv4.y))));
                        g4[2] = (bf16)(1.f / (1.f + __expf(-(cv[2] + bv4.z))));
                        g4[3] = (bf16)(1.f / (1.f + __expf(-(cv[3] + bv4.w))));
                        *(bf16x4*)(gb + (size_t)m * 512 + gcol) = g4;
                    }
                }
            }
        }
    } else {
        // V part, normal orientation: lane holds 4 consecutive qq for fixed d
        #pragma unroll
        for (int i = 0; i < MI; ++i) {
            const int m0 = bm + wm * (BM / 2) + i * 16 + quad * 4;
            const int b = m0 >> 11, qq0 = m0 & 2047;
            #pragma unroll
            for (int j = 0; j < NJ; ++j) {
                const int n = bn + wn * (BN / 2) + j * 16 + l15;
                const int h = (n >> 6) & 7, d = n & 63;
                const size_t off = (size_t)(b * H_ + h) * (Q_ * D_)
                    + (qq0 >> 6) * 4096 + (d >> 5) * 2048
                    + ((qq0 & 63) >> 4) * 512 + ((qq0 >> 3) & 1) * 256
                    + (d & 31) * 8 + (qq0 & 7);
                bf16x4 v4;
                #pragma unroll
                for (int r = 0; r < 4; ++r) v4[r] = (bf16)acc[i][j][r];
                *(bf16x4*)(vb + off) = v4;
            }
        }
    }
}

// ---------------------------------------------------------------------------
// Split-K(3, balanced 11/11/10) MFMA flash attention, 32x32x16, S^T/O^T.
// NO P LDS round-trip: the C-layout -> B-operand transform needs only data
// exchange between lanes l and l^32 -> 2 dword shfl_xor + cndmask per c4.
// LDS = K/V double-buffer only (32 KB) -> 3+ blocks/CU. glds staging,
// one barrier/step. No max-subtraction (scores bounded; exp2-safe in fp32);
// partials = unnormalized (sum pV, sum p) -> merge = add + divide.
// ---------------------------------------------------------------------------
__global__ __launch_bounds__(256, 3)
void attn_part(const bf16* __restrict__ qb, const bf16* __restrict__ kf,
               const bf16* __restrict__ vf, const float* __restrict__ bias,
               bf16* __restrict__ po, float* __restrict__ lsum)
{
    __shared__ __align__(16) bf16 Ks[2][4096];
    __shared__ __align__(16) bf16 Vs[2][4096];

    const int tid  = threadIdx.x;
    const int wv   = tid >> 6, lane = tid & 63;
    const int l31  = lane & 31, b5 = lane >> 5;
    const int x    = blockIdx.x;
    const int bh   = ((x & 7) << 1) | (x >> 3);   // XCD gets same-b head pair
    const int b    = bh >> 3;
    const int qg   = blockIdx.y * 128 + wv * 32 + l31;
    const int ks   = blockIdx.z;
    const int start   = ks * 11;                  // 0, 11, 22
    const int nsteps  = (ks == 2) ? 10 : 11;

    const bf16* qp = qb + ((size_t)bh * Q_ + qg) * D_;
    bf16x8 bq[4];
    #pragma unroll
    for (int c = 0; c < 4; ++c)
        bq[c] = *(const bf16x8*)(qp + c * 16 + b5 * 8);

    f32x16 acc[2] = {};
    float l_loc = 0.f;

    const bf16*  kfb  = kf + (size_t)bh * (Q_ * D_) + (size_t)start * 4096;
    const bf16*  vfb  = vf + (size_t)bh * (Q_ * D_) + (size_t)start * 4096;
    const float* brow = bias + ((size_t)b * Q_ + qg) * Q_ + start * 64;

    #pragma unroll
    for (int p = 0; p < 2; ++p) {
        gl_lds16(kfb + (wv * 2 + p) * 512 + lane * 8, Ks[0] + (wv * 2 + p) * 512);
        gl_lds16(vfb + (wv * 2 + p) * 512 + lane * 8, Vs[0] + (wv * 2 + p) * 512);
    }
    __asm__ volatile("s_waitcnt vmcnt(0)" ::: "memory");
    __syncthreads();

    int cur = 0;
    #pragma unroll 1
    for (int t = 0; t < nsteps; ++t) {
        if (t + 1 < nsteps) {
            const size_t off = (size_t)(t + 1) * 4096;
            #pragma unroll
            for (int p = 0; p < 2; ++p) {
                gl_lds16(kfb + off + (wv * 2 + p) * 512 + lane * 8,
                         Ks[cur ^ 1] + (wv * 2 + p) * 512);
                gl_lds16(vfb + off + (wv * 2 + p) * 512 + lane * 8,
                         Vs[cur ^ 1] + (wv * 2 + p) * 512);
            }
        }

        // ---- bias for this step (issued early; TLP hides L2 latency) ----
        f32x4 bc[8];
        #pragma unroll
        for (int i = 0; i < 8; ++i)
            bc[i] = *(const f32x4*)(brow + t * 64 + (i >> 2) * 32 + (i & 3) * 8 + b5 * 4);

        // ---- scores S^T ----
        const bf16* Kc = Ks[cur];
        f32x16 sv[2] = {};
        #pragma unroll
        for (int kg = 0; kg < 2; ++kg)
            #pragma unroll
            for (int c = 0; c < 4; ++c) {
                const bf16x8 ak = *(const bf16x8*)(Kc + kg * 2048 + c * 512 + lane * 8);
                sv[kg] = __builtin_amdgcn_mfma_f32_32x32x16_bf16(ak, bq[c], sv[kg], 0, 0, 0);
            }

        // ---- p = exp2(score + bias), no max-subtract ----
        float sc[2][16];
        float rs = 0.f;
        #pragma unroll
        for (int kg = 0; kg < 2; ++kg)
            #pragma unroll
            for (int r = 0; r < 16; ++r) {
                sc[kg][r] = __builtin_amdgcn_exp2f(
                    fmaf(bc[kg * 4 + (r >> 2)][r & 3], L2E, sv[kg][r]));
                rs += sc[kg][r];
            }
        l_loc += rs;

        // ---- P: C-layout -> B-operand via shfl_xor(32) + select; then PV ----
        const bf16* Vc = Vs[cur];
        #pragma unroll
        for (int c4 = 0; c4 < 4; ++c4) {
            const int kg = c4 >> 1;
            const int base = (c4 & 1) * 8;
            bf16x4 g0, g1;
            #pragma unroll
            for (int r = 0; r < 4; ++r) {
                g0[r] = (bf16)sc[kg][base + r];
                g1[r] = (bf16)sc[kg][base + 4 + r];
            }
            const bf16x4 snd = b5 ? g0 : g1;
            const bf16x4 rcv = shfl_xor32(snd);
            const bf16x4 lo  = b5 ? rcv : g0;
            const bf16x4 hi  = b5 ? g1  : rcv;
            bf16x8 bp;
            #pragma unroll
            for (int r = 0; r < 4; ++r) { bp[r] = lo[r]; bp[4 + r] = hi[r]; }
            #pragma unroll
            for (int dg = 0; dg < 2; ++dg) {
                const bf16x8 av = *(const bf16x8*)(Vc + dg * 2048 + c4 * 512 + lane * 8);
                acc[dg] = __builtin_amdgcn_mfma_f32_32x32x16_bf16(av, bp, acc[dg], 0, 0, 0);
            }
        }

        __asm__ volatile("s_waitcnt vmcnt(0)" ::: "memory");
        __syncthreads();
        cur ^= 1;
    }

    // ---- partial epilogue: unnormalized O (bf16) + row-sum l ----
    const float l_run = l_loc + __shfl_xor(l_loc, 32, 64);
    const size_t pbase = ((size_t)(ks * 16 + bh) * Q_ + qg) * 64;
    #pragma unroll
    for (int dg = 0; dg < 2; ++dg)
        #pragma unroll
        for (int gi = 0; gi < 4; ++gi) {
            const int d0 = dg * 32 + gi * 8 + b5 * 4;
            bf16x4 ov;
            #pragma unroll
            for (int r = 0; r < 4; ++r)
                ov[r] = (bf16)acc[dg][gi * 4 + r];
            *(bf16x4*)(po + pbase + d0) = ov;
        }
    if (b5 == 0)
        lsum[(size_t)(ks * 16 + bh) * Q_ + qg] = l_run;
}

// ---------------------------------------------------------------------------
// Merge 3 split-K partials, apply gate; writes gated O in-place into g.
// ---------------------------------------------------------------------------
__global__ __launch_bounds__(256)
void merge_kernel(const bf16* __restrict__ po, const float* __restrict__ lsum,
                  const bf16* g, bf16* og)
{
    const int gid = blockIdx.x * 256 + threadIdx.x;
    const int row = gid >> 3;             // bh*2048 + qg
    const int d8  = (gid & 7) * 8;
    const int bh  = row >> 11, qg = row & 2047;
    const int b   = bh >> 3, h = bh & 7;

    const float inv = 1.f / (lsum[row] + lsum[16 * Q_ + row] + lsum[32 * Q_ + row]);

    const bf16x8 o0 = *(const bf16x8*)(po + (size_t)row * 64 + d8);
    const bf16x8 o1 = *(const bf16x8*)(po + (size_t)16 * Q_ * 64 + (size_t)row * 64 + d8);
    const bf16x8 o2 = *(const bf16x8*)(po + (size_t)32 * Q_ * 64 + (size_t)row * 64 + d8);
    const size_t obase = ((size_t)(b * Q_ + qg)) * 512 + h * 64 + d8;
    const bf16x8 gv = *(const bf16x8*)(g + obase);
    bf16x8 ov;
    #pragma unroll
    for (int r = 0; r < 8; ++r)
        ov[r] = (bf16)(((float)o0[r] + (float)o1[r] + (float)o2[r]) * inv * (float)gv[r]);
    *(bf16x8*)(og + obase) = ov;
}

// ---------------------------------------------------------------------------
extern "C" void kernel_launch(void* const* d_in, const int* in_sizes, int n_in,
                              void* d_out, int out_size, void* d_ws, size_t ws_size,
                              hipStream_t stream)
{
    const float* q_x   = (const float*)d_in[0];
    const float* bias  = (const float*)d_in[2];
    const float* w_qkv = (const float*)d_in[3];
    const float* w_o   = (const float*)d_in[4];
    const float* b_o   = (const float*)d_in[5];
    const float* w_g   = (const float*)d_in[6];
    const float* b_g   = (const float*)d_in[7];
    float* out = (float*)d_out;

    char* ws = (char*)d_ws;
    bf16*  po   = (bf16*)(ws);                     // 12 MB partials (post-GEMM overlay)
    bf16*  qxb  = (bf16*)(ws);                     // 4 MB packed A (dead before attn)
    bf16*  wcat = (bf16*)(ws + (4u  << 20));       // 2 MB packed W (dead before attn)
    bf16*  qb   = (bf16*)(ws + (12u << 20));       // 4 MB q [B,H,Q,D]
    bf16*  kb   = (bf16*)(ws + (16u << 20));       // 4 MB K frag-ordered
    bf16*  vb   = (bf16*)(ws + (20u << 20));       // 4 MB V^T frag-ordered
    bf16*  gb   = (bf16*)(ws + (24u << 20));       // 4 MB gate -> gated O (in-place)
    bf16*  wob  = (bf16*)(ws + (28u << 20));       // 0.5 MB packed W_o
    float* lsum = (float*)(ws + (28u << 20) + (1u << 19));  // 384 KB

    // 1) fp32 -> bf16 conversions into K-panel-packed layouts
    convert_kernel<<<(S0 + S1 + S2 + S3) / (256 * 8), 256, 0, stream>>>(
        q_x, w_qkv, w_g, w_o, qxb, wcat, wob);
    // 2) fused QKV + gate projection (double-buffered K-loop)
    gemm_bf16<128, 64, 0, 2048, 1><<<dim3(32, 32), 256, 0, stream>>>(
        qxb, wcat, b_g, nullptr, qb, kb, vb, gb);
    // 3) split-K(3, balanced) flash attention, no-Ps shuffle transform
    attn_part<<<dim3(B_ * H_, Q_ / 128, 3), 256, 0, stream>>>(qb, kb, vb, bias, po, lsum);
    // 4) merge partials + gate (in-place into gb)
    merge_kernel<<<(16 * Q_ * 8) / 256, 256, 0, stream>>>(po, lsum, gb, gb);
    // 5) output projection + b_o (double-buffered; A row-major, W packed)
    gemm_bf16<64, 64, 1, 512, 0><<<dim3(64, 8), 256, 0, stream>>>(
        gb, wob, b_o, out, nullptr, nullptr, nullptr, nullptr);
}

// Round 11
// 180.298 us; speedup vs baseline: 1.0391x; 1.0391x over previous
//
#include <hip/hip_runtime.h>
#include <math.h>

#define B_  2
#define Q_  2048
#define CQ_ 512
#define H_  8
#define D_  64
#define M_  (B_*Q_)   // 4096
#define L2E 1.44269504088896f

typedef __bf16 bf16;
typedef __bf16 bf16x4 __attribute__((ext_vector_type(4)));
typedef __bf16 bf16x8 __attribute__((ext_vector_type(8)));
typedef float  f32x4  __attribute__((ext_vector_type(4)));
typedef float  f32x16 __attribute__((ext_vector_type(16)));

// async global->LDS, 16 bytes per lane; lds dest = wave-uniform base + lane*16
__device__ __forceinline__ void gl_lds16(const bf16* g, bf16* l) {
    __builtin_amdgcn_global_load_lds(
        (const __attribute__((address_space(1))) unsigned int*)g,
        (__attribute__((address_space(3))) unsigned int*)l, 16, 0, 0);
}

__device__ __forceinline__ bf16x4 shfl_xor32(bf16x4 v) {
    union { bf16x4 h; int i[2]; } u;
    u.h = v;
    u.i[0] = __shfl_xor(u.i[0], 32, 64);
    u.i[1] = __shfl_xor(u.i[1], 32, 64);
    return u.h;
}

// ---------------------------------------------------------------------------
// fp32 -> bf16 conversion into K-panel-packed layouts (pack = LDS image):
//   pack_off(row, k; R) = (k>>5)*(R*32) + row*32 + (k&31)
// ---------------------------------------------------------------------------
#define S0 (4096*512)    // q_x
#define S1 (1536*512)    // w_qkv
#define S2 (512*512)     // w_g
#define S3 (512*512)     // w_o
__global__ __launch_bounds__(256)
void convert_kernel(const float* __restrict__ qx, const float* __restrict__ wqkv,
                    const float* __restrict__ wg, const float* __restrict__ wo,
                    bf16* __restrict__ qxb, bf16* __restrict__ wcat, bf16* __restrict__ wob)
{
    const long long t = (long long)blockIdx.x * 256 + threadIdx.x;
    const long long e = t * 8;
    const float* src; bf16* dst;
    if (e < S0) {
        const int m = (int)(e >> 9), k = (int)(e & 511);
        src = qx + e;
        dst = qxb + (size_t)(k >> 5) * (4096 * 32) + (size_t)m * 32 + (k & 31);
    } else if (e < S0 + S1) {
        const long long e2 = e - S0;
        const int n = (int)(e2 >> 9), k = (int)(e2 & 511);
        src = wqkv + e2;
        dst = wcat + (size_t)(k >> 5) * (2048 * 32) + (size_t)n * 32 + (k & 31);
    } else if (e < S0 + S1 + S2) {
        const long long e2 = e - S0 - S1;
        const int n = 1536 + (int)(e2 >> 9), k = (int)(e2 & 511);
        src = wg + e2;
        dst = wcat + (size_t)(k >> 5) * (2048 * 32) + (size_t)n * 32 + (k & 31);
    } else {
        const long long e2 = e - S0 - S1 - S2;
        const int n = (int)(e2 >> 9), k = (int)(e2 & 511);
        src = wo + e2;
        dst = wob + (size_t)(k >> 5) * (512 * 32) + (size_t)n * 32 + (k & 31);
    }
    const float4 a = *(const float4*)(src);
    const float4 b = *(const float4*)(src + 4);
    bf16x8 v;
    v[0] = (bf16)a.x; v[1] = (bf16)a.y; v[2] = (bf16)a.z; v[3] = (bf16)a.w;
    v[4] = (bf16)b.x; v[5] = (bf16)b.y; v[6] = (bf16)b.z; v[7] = (bf16)b.w;
    *(bf16x8*)dst = v;
}

// bias fp32 -> bf16 prescaled by log2e (halves attn's dominant byte stream)
__global__ __launch_bounds__(256)
void convert_bias(const float* __restrict__ bias, bf16* __restrict__ biasb)
{
    const size_t e = ((size_t)blockIdx.x * 256 + threadIdx.x) * 8;
    const float4 a = *(const float4*)(bias + e);
    const float4 b = *(const float4*)(bias + e + 4);
    bf16x8 v;
    v[0] = (bf16)(a.x * L2E); v[1] = (bf16)(a.y * L2E);
    v[2] = (bf16)(a.z * L2E); v[3] = (bf16)(a.w * L2E);
    v[4] = (bf16)(b.x * L2E); v[5] = (bf16)(b.y * L2E);
    v[6] = (bf16)(b.z * L2E); v[7] = (bf16)(b.w * L2E);
    *(bf16x8*)(biasb + e) = v;
}

// ---------------------------------------------------------------------------
// bf16 MFMA GEMM, DEPTH-2 pipeline: 3 LDS buffers; raw s_barrier with
// per-wave s_waitcnt vmcnt(G) (never 0 mid-loop) -> tile k+2 stays in
// flight across the barrier; only tile k+1 must have landed.
// C[M,N] = A[M,512]*W[N,512]^T, BK=32. All parts except V compute C^T.
// ---------------------------------------------------------------------------
template<int BM, int BN, int EPI, int WNR, int APACK>
__global__ __launch_bounds__(256)
void gemm_bf16(const bf16* __restrict__ A, const bf16* __restrict__ W,
               const float* __restrict__ bvec, float* __restrict__ fout,
               bf16* __restrict__ qb, bf16* __restrict__ kb, bf16* __restrict__ vb,
               bf16* __restrict__ gb)
{
    constexpr int MI = BM / 32, NJ = BN / 32;
    constexpr int APARTS = BM / 16, BPARTS = BN / 16, NPARTS = APARTS + BPARTS;
    constexpr int G = NPARTS / 4;                 // glds per wave per stage
    __shared__ __align__(16) bf16 As[3][BM * 32];
    __shared__ __align__(16) bf16 Bs[3][BN * 32];

    const int t = threadIdx.x;
    const int w = t >> 6, lane = t & 63;
    const int l15 = lane & 15, quad = lane >> 4;
    const int wm = w & 1, wn = w >> 1;
    const int bm = blockIdx.x * BM;
    const int bn = blockIdx.y * BN;
    const bool swapped = (EPI == 1) || ((bn >> 9) != 2);

    f32x4 acc[MI][NJ] = {};

    auto stage = [&](int kp) {
        bf16* Ad = As[kp % 3];
        bf16* Bd = Bs[kp % 3];
        #pragma unroll
        for (int idx = 0; idx < G; ++idx) {
            const int p = idx * 4 + w;
            if (p < APARTS) {
                if constexpr (APACK)
                    gl_lds16(A + (size_t)kp * (4096 * 32) + (size_t)bm * 32 + p * 512 + lane * 8,
                             Ad + p * 512);
                else
                    gl_lds16(A + (size_t)(bm + p * 16 + (lane >> 2)) * 512 + kp * 32 + (lane & 3) * 8,
                             Ad + p * 512);
            } else {
                gl_lds16(W + (size_t)kp * (WNR * 32) + (size_t)bn * 32 + (p - APARTS) * 512 + lane * 8,
                         Bd + (p - APARTS) * 512);
            }
        }
    };

    stage(0);
    stage(1);

    #pragma unroll 1
    for (int kp = 0; kp < 16; ++kp) {
        if (kp == 15) __builtin_amdgcn_s_waitcnt(0x0F70);
        else          __builtin_amdgcn_s_waitcnt(0x0F70 | G);
        __builtin_amdgcn_s_barrier();
        __asm__ volatile("" ::: "memory");

        const bf16* Ac = As[kp % 3];
        const bf16* Bc = Bs[kp % 3];
        bf16x8 af[MI], bfr[NJ];
        #pragma unroll
        for (int i = 0; i < MI; ++i)
            af[i] = *(const bf16x8*)(Ac + (wm * (BM / 2) + i * 16 + l15) * 32 + quad * 8);
        #pragma unroll
        for (int j = 0; j < NJ; ++j)
            bfr[j] = *(const bf16x8*)(Bc + (wn * (BN / 2) + j * 16 + l15) * 32 + quad * 8);
        if (swapped) {
            #pragma unroll
            for (int i = 0; i < MI; ++i)
                #pragma unroll
                for (int j = 0; j < NJ; ++j)
                    acc[i][j] = __builtin_amdgcn_mfma_f32_16x16x32_bf16(bfr[j], af[i], acc[i][j], 0, 0, 0);
        } else {
            #pragma unroll
            for (int i = 0; i < MI; ++i)
                #pragma unroll
                for (int j = 0; j < NJ; ++j)
                    acc[i][j] = __builtin_amdgcn_mfma_f32_16x16x32_bf16(af[i], bfr[j], acc[i][j], 0, 0, 0);
        }

        if (kp + 2 < 16) stage(kp + 2);
    }

    if (swapped) {
        #pragma unroll
        for (int i = 0; i < MI; ++i) {
            const int m = bm + wm * (BM / 2) + i * 16 + l15;
            const int b = m >> 11, qq = m & 2047;
            #pragma unroll
            for (int j = 0; j < NJ; ++j) {
                const int n0 = bn + wn * (BN / 2) + j * 16 + quad * 4;
                const f32x4 cv = acc[i][j];
                if constexpr (EPI == 1) {
                    float4 st;
                    st.x = cv[0] + bvec[n0 + 0];
                    st.y = cv[1] + bvec[n0 + 1];
                    st.z = cv[2] + bvec[n0 + 2];
                    st.w = cv[3] + bvec[n0 + 3];
                    *(float4*)(fout + (size_t)m * 512 + n0) = st;
                } else {
                    const int part = n0 >> 9;
                    if (part == 0) {
                        const int h = (n0 >> 6) & 7, d0 = n0 & 63;
                        bf16x4 q4;
                        #pragma unroll
                        for (int r = 0; r < 4; ++r) q4[r] = (bf16)(cv[r] * (0.125f * L2E));
                        *(bf16x4*)(qb + (size_t)(b * H_ + h) * (Q_ * D_) + (size_t)qq * 64 + d0) = q4;
                    } else if (part == 1) {
                        const int h = (n0 >> 6) & 7, d0 = n0 & 63;
                        const size_t off = (size_t)(b * H_ + h) * (Q_ * D_)
                            + (qq >> 6) * 4096 + ((qq >> 5) & 1) * 2048
                            + (d0 >> 4) * 512 + ((d0 >> 3) & 1) * 256
                            + (qq & 31) * 8 + (d0 & 7);
                        bf16x4 k4;
                        #pragma unroll
                        for (int r = 0; r < 4; ++r) k4[r] = (bf16)cv[r];
                        *(bf16x4*)(kb + off) = k4;
                    } else {
                        const int gcol = n0 & 511;
                        const float4 bv4 = *(const float4*)(bvec + gcol);
                        bf16x4 g4;
                        g4[0] = (bf16)(1.f / (1.f + __expf(-(cv[0] + bv4.x))));
                        g4[1] = (bf16)(1.f / (1.f + __expf(-(cv[1] + bv4.y))));
                        g4[2] = (bf16)(1.f / (1.f + __expf(-(cv[2] + bv4.z))));
                        g4[3] = (bf16)(1.f / (1.f + __expf(-(cv[3] + bv4.w))));
                        *(bf16x4*)(gb + (size_t)m * 512 + gcol) = g4;
                    }
                }
            }
        }
    } else {
        #pragma unroll
        for (int i = 0; i < MI; ++i) {
            const int m0 = bm + wm * (BM / 2) + i * 16 + quad * 4;
            const int b = m0 >> 11, qq0 = m0 & 2047;
            #pragma unroll
            for (int j = 0; j < NJ; ++j) {
                const int n = bn + wn * (BN / 2) + j * 16 + l15;
                const int h = (n >> 6) & 7, d = n & 63;
                const size_t off = (size_t)(b * H_ + h) * (Q_ * D_)
                    + (qq0 >> 6) * 4096 + (d >> 5) * 2048
                    + ((qq0 & 63) >> 4) * 512 + ((qq0 >> 3) & 1) * 256
                    + (d & 31) * 8 + (qq0 & 7);
                bf16x4 v4;
                #pragma unroll
                for (int r = 0; r < 4; ++r) v4[r] = (bf16)acc[i][j][r];
                *(bf16x4*)(vb + off) = v4;
            }
        }
    }
}

// ---------------------------------------------------------------------------
// Split-K(3) MFMA flash attention, 32x32x16, S^T/O^T, shuffle-P (0 conflicts).
// DEPTH-2 glds pipeline: 3 K/V buffers; per step issue order is
// [compute | bias(t+1) regs (8 vmem) | glds(t+2) (4 vmem)], so the top-of-step
// wait vmcnt(12) guarantees tile t landed while leaving bias(t)+glds(t+1)
// in flight (vmcnt(8) on the last step). Bias as bf16 (prescaled by log2e)
// folded into the MFMA C-operand init when BB=1.
// ---------------------------------------------------------------------------
template<int BB>
__global__ __launch_bounds__(256, 3)
void attn_part(const bf16* __restrict__ qb, const bf16* __restrict__ kf,
               const bf16* __restrict__ vf, const void* __restrict__ biasp,
               bf16* __restrict__ po, float* __restrict__ lsum)
{
    __shared__ __align__(16) bf16 Ks[3][4096];
    __shared__ __align__(16) bf16 Vs[3][4096];

    const int tid  = threadIdx.x;
    const int wv   = tid >> 6, lane = tid & 63;
    const int l31  = lane & 31, b5 = lane >> 5;
    const int x    = blockIdx.x;
    const int bh   = ((x & 7) << 1) | (x >> 3);   // XCD gets same-b head pair
    const int b    = bh >> 3;
    const int qg   = blockIdx.y * 128 + wv * 32 + l31;
    const int ks   = blockIdx.z;
    const int start  = ks * 11;                   // 0, 11, 22
    const int nsteps = (ks == 2) ? 10 : 11;

    const bf16* qp = qb + ((size_t)bh * Q_ + qg) * D_;
    bf16x8 bq[4];
    #pragma unroll
    for (int c = 0; c < 4; ++c)
        bq[c] = *(const bf16x8*)(qp + c * 16 + b5 * 8);

    f32x16 acc[2] = {};
    float l_loc = 0.f;

    const bf16*  kfb   = kf + (size_t)bh * (Q_ * D_) + (size_t)start * 4096;
    const bf16*  vfb   = vf + (size_t)bh * (Q_ * D_) + (size_t)start * 4096;
    const bf16*  browh = (const bf16*)biasp  + ((size_t)b * Q_ + qg) * Q_ + start * 64;
    const float* browf = (const float*)biasp + ((size_t)b * Q_ + qg) * Q_ + start * 64;

    auto stageKV = [&](int tt) {
        const size_t off = (size_t)tt * 4096;
        bf16* Kd = Ks[tt % 3];
        bf16* Vd = Vs[tt % 3];
        #pragma unroll
        for (int p = 0; p < 2; ++p) {
            gl_lds16(kfb + off + (wv * 2 + p) * 512 + lane * 8, Kd + (wv * 2 + p) * 512);
            gl_lds16(vfb + off + (wv * 2 + p) * 512 + lane * 8, Vd + (wv * 2 + p) * 512);
        }
    };

    bf16x4 bbh[8];
    f32x4  bbf[8];
    auto loadBias = [&](int tt) {
        #pragma unroll
        for (int i = 0; i < 8; ++i) {
            const int o = tt * 64 + (i >> 2) * 32 + (i & 3) * 8 + b5 * 4;
            if constexpr (BB) bbh[i] = *(const bf16x4*)(browh + o);
            else              bbf[i] = *(const f32x4*)(browf + o);
        }
    };

    stageKV(0);
    stageKV(1);
    loadBias(0);

    #pragma unroll 1
    for (int t = 0; t < nsteps; ++t) {
        if (t == nsteps - 1) __builtin_amdgcn_s_waitcnt(0x0F78);   // vmcnt(8)
        else                 __builtin_amdgcn_s_waitcnt(0x0F7C);   // vmcnt(12)
        __builtin_amdgcn_s_barrier();
        __asm__ volatile("" ::: "memory");

        // ---- scores S^T, bias in the MFMA C operand ----
        const bf16* Kc = Ks[t % 3];
        f32x16 sv[2];
        #pragma unroll
        for (int kg = 0; kg < 2; ++kg)
            #pragma unroll
            for (int r = 0; r < 16; ++r)
                sv[kg][r] = BB ? (float)bbh[kg * 4 + (r >> 2)][r & 3]
                               : bbf[kg * 4 + (r >> 2)][r & 3] * L2E;
        #pragma unroll
        for (int kg = 0; kg < 2; ++kg)
            #pragma unroll
            for (int c = 0; c < 4; ++c) {
                const bf16x8 ak = *(const bf16x8*)(Kc + kg * 2048 + c * 512 + lane * 8);
                sv[kg] = __builtin_amdgcn_mfma_f32_32x32x16_bf16(ak, bq[c], sv[kg], 0, 0, 0);
            }

        // ---- p = exp2(score), no max-subtract ----
        float sc[2][16];
        float rs = 0.f;
        #pragma unroll
        for (int kg = 0; kg < 2; ++kg)
            #pragma unroll
            for (int r = 0; r < 16; ++r) {
                sc[kg][r] = __builtin_amdgcn_exp2f(sv[kg][r]);
                rs += sc[kg][r];
            }
        l_loc += rs;

        // ---- P: C-layout -> B-operand via shfl_xor(32) + select; then PV ----
        const bf16* Vc = Vs[t % 3];
        #pragma unroll
        for (int c4 = 0; c4 < 4; ++c4) {
            const int kg = c4 >> 1;
            const int base = (c4 & 1) * 8;
            bf16x4 g0, g1;
            #pragma unroll
            for (int r = 0; r < 4; ++r) {
                g0[r] = (bf16)sc[kg][base + r];
                g1[r] = (bf16)sc[kg][base + 4 + r];
            }
            const bf16x4 snd = b5 ? g0 : g1;
            const bf16x4 rcv = shfl_xor32(snd);
            const bf16x4 lo  = b5 ? rcv : g0;
            const bf16x4 hi  = b5 ? g1  : rcv;
            bf16x8 bp;
            #pragma unroll
            for (int r = 0; r < 4; ++r) { bp[r] = lo[r]; bp[4 + r] = hi[r]; }
            #pragma unroll
            for (int dg = 0; dg < 2; ++dg) {
                const bf16x8 av = *(const bf16x8*)(Vc + dg * 2048 + c4 * 512 + lane * 8);
                acc[dg] = __builtin_amdgcn_mfma_f32_32x32x16_bf16(av, bp, acc[dg], 0, 0, 0);
            }
        }

        // ---- prefetch: bias for t+1 (8 vmem), then K/V tile t+2 (4 glds) ----
        if (t + 1 < nsteps) loadBias(t + 1);
        if (t + 2 < nsteps) stageKV(t + 2);
    }

    // ---- partial epilogue: unnormalized O (bf16) + row-sum l ----
    const float l_run = l_loc + __shfl_xor(l_loc, 32, 64);
    const size_t pbase = ((size_t)(ks * 16 + bh) * Q_ + qg) * 64;
    #pragma unroll
    for (int dg = 0; dg < 2; ++dg)
        #pragma unroll
        for (int gi = 0; gi < 4; ++gi) {
            const int d0 = dg * 32 + gi * 8 + b5 * 4;
            bf16x4 ov;
            #pragma unroll
            for (int r = 0; r < 4; ++r)
                ov[r] = (bf16)acc[dg][gi * 4 + r];
            *(bf16x4*)(po + pbase + d0) = ov;
        }
    if (b5 == 0)
        lsum[(size_t)(ks * 16 + bh) * Q_ + qg] = l_run;
}

// ---------------------------------------------------------------------------
// Merge 3 split-K partials, apply gate; writes gated O in-place into g.
// ---------------------------------------------------------------------------
__global__ __launch_bounds__(256)
void merge_kernel(const bf16* __restrict__ po, const float* __restrict__ lsum,
                  const bf16* g, bf16* og)
{
    const int gid = blockIdx.x * 256 + threadIdx.x;
    const int row = gid >> 3;             // bh*2048 + qg
    const int d8  = (gid & 7) * 8;
    const int bh  = row >> 11, qg = row & 2047;
    const int b   = bh >> 3, h = bh & 7;

    const float inv = 1.f / (lsum[row] + lsum[16 * Q_ + row] + lsum[32 * Q_ + row]);

    const bf16x8 o0 = *(const bf16x8*)(po + (size_t)row * 64 + d8);
    const bf16x8 o1 = *(const bf16x8*)(po + (size_t)16 * Q_ * 64 + (size_t)row * 64 + d8);
    const bf16x8 o2 = *(const bf16x8*)(po + (size_t)32 * Q_ * 64 + (size_t)row * 64 + d8);
    const size_t obase = ((size_t)(b * Q_ + qg)) * 512 + h * 64 + d8;
    const bf16x8 gv = *(const bf16x8*)(g + obase);
    bf16x8 ov;
    #pragma unroll
    for (int r = 0; r < 8; ++r)
        ov[r] = (bf16)(((float)o0[r] + (float)o1[r] + (float)o2[r]) * inv * (float)gv[r]);
    *(bf16x8*)(og + obase) = ov;
}

// ---------------------------------------------------------------------------
extern "C" void kernel_launch(void* const* d_in, const int* in_sizes, int n_in,
                              void* d_out, int out_size, void* d_ws, size_t ws_size,
                              hipStream_t stream)
{
    const float* q_x   = (const float*)d_in[0];
    const float* bias  = (const float*)d_in[2];
    const float* w_qkv = (const float*)d_in[3];
    const float* w_o   = (const float*)d_in[4];
    const float* b_o   = (const float*)d_in[5];
    const float* w_g   = (const float*)d_in[6];
    const float* b_g   = (const float*)d_in[7];
    float* out = (float*)d_out;

    char* ws = (char*)d_ws;
    bf16*  po    = (bf16*)(ws);                    // 12 MB partials (post-GEMM overlay)
    bf16*  qxb   = (bf16*)(ws);                    // 4 MB packed A (dead before attn)
    bf16*  wcat  = (bf16*)(ws + (4u  << 20));      // 2 MB packed W (dead before attn)
    bf16*  qb    = (bf16*)(ws + (12u << 20));      // 4 MB q [B,H,Q,D]
    bf16*  kb    = (bf16*)(ws + (16u << 20));      // 4 MB K frag-ordered
    bf16*  vb    = (bf16*)(ws + (20u << 20));      // 4 MB V^T frag-ordered
    bf16*  gb    = (bf16*)(ws + (24u << 20));      // 4 MB gate -> gated O (in-place)
    bf16*  wob   = (bf16*)(ws + (28u << 20));      // 0.5 MB packed W_o
    float* lsum  = (float*)(ws + (28u << 20) + (1u << 19));  // 384 KB
    bf16*  biasb = (bf16*)(ws + (29u << 20));      // 16.8 MB (conditional)

    const bool use_bb = ws_size >= (46ull << 20);  // ws_size is constant per process

    // 1) fp32 -> bf16 conversions into K-panel-packed layouts (+ bias bf16)
    convert_kernel<<<(S0 + S1 + S2 + S3) / (256 * 8), 256, 0, stream>>>(
        q_x, w_qkv, w_g, w_o, qxb, wcat, wob);
    if (use_bb)
        convert_bias<<<(2 * Q_ * Q_) / (256 * 8), 256, 0, stream>>>(bias, biasb);
    // 2) fused QKV + gate projection (depth-2 pipeline, 128x128)
    gemm_bf16<128, 128, 0, 2048, 1><<<dim3(32, 16), 256, 0, stream>>>(
        qxb, wcat, b_g, nullptr, qb, kb, vb, gb);
    // 3) split-K(3) flash attention (depth-2 glds pipeline, bf16 bias)
    if (use_bb)
        attn_part<1><<<dim3(B_ * H_, Q_ / 128, 3), 256, 0, stream>>>(
            qb, kb, vb, biasb, po, lsum);
    else
        attn_part<0><<<dim3(B_ * H_, Q_ / 128, 3), 256, 0, stream>>>(
            qb, kb, vb, bias, po, lsum);
    // 4) merge partials + gate (in-place into gb)
    merge_kernel<<<(16 * Q_ * 8) / 256, 256, 0, stream>>>(po, lsum, gb, gb);
    // 5) output projection + b_o (depth-2 pipeline)
    gemm_bf16<64, 64, 1, 512, 0><<<dim3(64, 8), 256, 0, stream>>>(
        gb, wob, b_o, out, nullptr, nullptr, nullptr, nullptr);
}